// Round 1
// baseline (111.988 us; speedup 1.0000x reference)
//
#include <hip/hip_runtime.h>

#define B_   4
#define K_   6
#define BK_  (B_ * K_)
#define C_   128
#define HF_  32
#define WF_  88
#define P_   (HF_ * WF_)      // 2816 pixels per (b,k) feature map
#define BEV  256
#define NPTS (BEV * BEV)      // 65536

// ---------------------------------------------------------------------------
// Kernel 1: transpose features [BK, C, P] -> [BK, P, C] so channel is the
// fastest-varying dim (contiguous float4 gathers in the projector).
// LDS-tiled: coalesced reads (lanes over pixels) and coalesced writes
// (lanes over channels). Pad inner dim +1 to avoid 32-way bank conflicts.
// ---------------------------------------------------------------------------
__global__ __launch_bounds__(256) void transpose_feat(
    const float* __restrict__ in, float* __restrict__ outT)
{
    __shared__ float lds[64][C_ + 1];
    const int bk  = blockIdx.y;
    const int p0  = blockIdx.x * 64;
    const int tid = threadIdx.x;

    const int pl = tid & 63;        // pixel within tile (read phase)
    const int cq = tid >> 6;        // 0..3 channel sub-lane (read phase)
    const float* src = in + (size_t)bk * C_ * P_;
#pragma unroll
    for (int c0 = 0; c0 < C_; c0 += 4) {
        const int c = c0 + cq;
        lds[pl][c] = src[(size_t)c * P_ + p0 + pl];
    }
    __syncthreads();

    float* dst = outT + ((size_t)bk * P_ + p0) * C_;
    const int cl = tid & 127;       // channel (write phase)
    const int ph = tid >> 7;        // 0..1 pixel sub-lane (write phase)
#pragma unroll
    for (int p2 = 0; p2 < 32; ++p2) {
        const int p = p2 * 2 + ph;
        dst[(size_t)p * C_ + cl] = lds[p][cl];
    }
}

// ---------------------------------------------------------------------------
// Kernel 2: per-BEV-point projection + bilinear sampling over 6 cameras.
// One thread per BEV point; block = one BEV row (ix = lane -> coalesced
// output stores per channel plane). Geometry once into registers; channel
// loop in float4 chunks (TRANS layout) or scalar (fallback).
// ---------------------------------------------------------------------------
template <bool TRANS>
__global__ __launch_bounds__(256) void bev_project(
    const float* __restrict__ feat,
    const float* __restrict__ intr,   // [B,K,3,3]
    const float* __restrict__ extr,   // [B,K,4,4]
    float* __restrict__ out)          // [B,C,BEV,BEV]
{
    const int ix = threadIdx.x;
    const int iy = blockIdx.x;
    const int b  = blockIdx.y;

    const float STEP = 102.4f / 255.0f;
    const float gx = -51.2f + ix * STEP;
    const float gy = -51.2f + iy * STEP;

    int   off[K_], dX[K_], dY[K_];
    float w00[K_], w01[K_], w10[K_], w11[K_];
    bool  val[K_];
    float cnt = 0.0f;

#pragma unroll
    for (int k = 0; k < K_; ++k) {
        const float* E = extr + (size_t)(b * K_ + k) * 16;
        const float* I = intr + (size_t)(b * K_ + k) * 9;
        // world z = 0, w = 1
        const float c0 = E[0] * gx + E[1] * gy + E[3];
        const float c1 = E[4] * gx + E[5] * gy + E[7];
        const float c2 = E[8] * gx + E[9] * gy + E[11];
        const float uu = I[0] * c0 + I[1] * c1 + I[2] * c2;
        const float vv = I[3] * c0 + I[4] * c1 + I[5] * c2;
        const float ww = I[6] * c0 + I[7] * c1 + I[8] * c2;
        const float depth = fmaxf(ww, 1e-5f);
        const float u = uu / depth * 0.125f;   // sx = 88/704
        const float v = vv / depth * 0.125f;   // sy = 32/256
        const bool valid = (ww > 1e-3f) && (u >= 0.0f) && (u <= (float)(WF_ - 1))
                                        && (v >= 0.0f) && (v <= (float)(HF_ - 1));
        const float uc = fminf(fmaxf(u, 0.0f), (float)(WF_ - 1));
        const float vc = fminf(fmaxf(v, 0.0f), (float)(HF_ - 1));
        const float x0f = floorf(uc), y0f = floorf(vc);
        const int x0 = (int)x0f, y0 = (int)y0f;
        const int x1 = min(x0 + 1, WF_ - 1), y1 = min(y0 + 1, HF_ - 1);
        const float wx = uc - x0f, wy = vc - y0f;

        val[k] = valid;
        cnt += valid ? 1.0f : 0.0f;
        w00[k] = (1.0f - wx) * (1.0f - wy);
        w01[k] = wx * (1.0f - wy);
        w10[k] = (1.0f - wx) * wy;
        w11[k] = wx * wy;

        const int pix = y0 * WF_ + x0;
        if (TRANS) {
            off[k] = ((b * K_ + k) * P_ + pix) * C_;
            dX[k]  = (x1 - x0) * C_;
            dY[k]  = (y1 - y0) * (WF_ * C_);
        } else {
            off[k] = (b * K_ + k) * (C_ * P_) + pix;
            dX[k]  = (x1 - x0);
            dY[k]  = (y1 - y0) * WF_;
        }
    }

    const float inv = 1.0f / fmaxf(cnt, 1.0f);
    float* outp = out + (size_t)b * C_ * NPTS + (size_t)iy * BEV + ix;

    if (TRANS) {
#pragma unroll 1
        for (int c = 0; c < C_; c += 4) {
            float ax = 0.0f, ay = 0.0f, az = 0.0f, aw = 0.0f;
#pragma unroll
            for (int k = 0; k < K_; ++k) {
                if (!val[k]) continue;
                const float* pb = feat + off[k] + c;
                const float4 f00 = *(const float4*)(pb);
                const float4 f01 = *(const float4*)(pb + dX[k]);
                const float4 f10 = *(const float4*)(pb + dY[k]);
                const float4 f11 = *(const float4*)(pb + dX[k] + dY[k]);
                ax += w00[k] * f00.x + w01[k] * f01.x + w10[k] * f10.x + w11[k] * f11.x;
                ay += w00[k] * f00.y + w01[k] * f01.y + w10[k] * f10.y + w11[k] * f11.y;
                az += w00[k] * f00.z + w01[k] * f01.z + w10[k] * f10.z + w11[k] * f11.z;
                aw += w00[k] * f00.w + w01[k] * f01.w + w10[k] * f10.w + w11[k] * f11.w;
            }
            outp[(size_t)(c + 0) * NPTS] = ax * inv;
            outp[(size_t)(c + 1) * NPTS] = ay * inv;
            outp[(size_t)(c + 2) * NPTS] = az * inv;
            outp[(size_t)(c + 3) * NPTS] = aw * inv;
        }
    } else {
#pragma unroll 1
        for (int c = 0; c < C_; ++c) {
            float a = 0.0f;
#pragma unroll
            for (int k = 0; k < K_; ++k) {
                if (!val[k]) continue;
                const float* pb = feat + off[k] + c * P_;
                a += w00[k] * pb[0] + w01[k] * pb[dX[k]]
                   + w10[k] * pb[dY[k]] + w11[k] * pb[dX[k] + dY[k]];
            }
            outp[(size_t)c * NPTS] = a * inv;
        }
    }
}

extern "C" void kernel_launch(void* const* d_in, const int* in_sizes, int n_in,
                              void* d_out, int out_size, void* d_ws, size_t ws_size,
                              hipStream_t stream) {
    const float* features   = (const float*)d_in[0];
    const float* intrinsics = (const float*)d_in[1];
    const float* extrinsics = (const float*)d_in[2];
    float* out = (float*)d_out;

    const size_t need = sizeof(float) * (size_t)BK_ * C_ * P_;  // ~33 MB
    if (ws_size >= need) {
        float* featT = (float*)d_ws;
        transpose_feat<<<dim3(P_ / 64, BK_), 256, 0, stream>>>(features, featT);
        bev_project<true><<<dim3(BEV, B_), 256, 0, stream>>>(featT, intrinsics, extrinsics, out);
    } else {
        bev_project<false><<<dim3(BEV, B_), 256, 0, stream>>>(features, intrinsics, extrinsics, out);
    }
}

// Round 2
// 92.267 us; speedup vs baseline: 1.2137x; 1.2137x over previous
//
#include <hip/hip_runtime.h>

#define B_   4
#define K_   6
#define BK_  (B_ * K_)
#define C_   128
#define HF_  32
#define WF_  88
#define P_   (HF_ * WF_)      // 2816 pixels per (b,k) feature map
#define BEV  256
#define NPTS (BEV * BEV)      // 65536
#define CSPLIT 4              // channel slices (grid.z)
#define CPT  (C_ / CSPLIT)    // 32 channels per thread

// ---------------------------------------------------------------------------
// Kernel 1: transpose features [BK, C, P] -> [BK, P, C] so channel is the
// fastest-varying dim (contiguous float4 gathers in the projector).
// ---------------------------------------------------------------------------
__global__ __launch_bounds__(256) void transpose_feat(
    const float* __restrict__ in, float* __restrict__ outT)
{
    __shared__ float lds[64][C_ + 1];
    const int bk  = blockIdx.y;
    const int p0  = blockIdx.x * 64;
    const int tid = threadIdx.x;

    const int pl = tid & 63;        // pixel within tile (read phase)
    const int cq = tid >> 6;        // 0..3 channel sub-lane (read phase)
    const float* src = in + (size_t)bk * C_ * P_;
#pragma unroll
    for (int c0 = 0; c0 < C_; c0 += 4) {
        const int c = c0 + cq;
        lds[pl][c] = src[(size_t)c * P_ + p0 + pl];
    }
    __syncthreads();

    float* dst = outT + ((size_t)bk * P_ + p0) * C_;
    const int cl = tid & 127;       // channel (write phase)
    const int ph = tid >> 7;        // 0..1 pixel sub-lane (write phase)
#pragma unroll
    for (int p2 = 0; p2 < 32; ++p2) {
        const int p = p2 * 2 + ph;
        dst[(size_t)p * C_ + cl] = lds[p][cl];
    }
}

// ---------------------------------------------------------------------------
// Kernel 2: per-BEV-point projection + bilinear sampling over 6 cameras.
// Grid: (BEV rows, B, CSPLIT channel slices); block: 256 threads (ix lane).
// Geometry recomputed per slice (cheap); channel loop = 8 float4 chunks.
// Nontemporal output stores keep L2 free for the gather-heavy feature reads.
// ---------------------------------------------------------------------------
template <bool TRANS>
__global__ __launch_bounds__(256) void bev_project(
    const float* __restrict__ feat,
    const float* __restrict__ intr,   // [B,K,3,3]
    const float* __restrict__ extr,   // [B,K,4,4]
    float* __restrict__ out)          // [B,C,BEV,BEV]
{
    const int ix = threadIdx.x;
    const int iy = blockIdx.x;
    const int b  = blockIdx.y;
    const int cs = blockIdx.z;

    const float STEP = 102.4f / 255.0f;
    const float gx = -51.2f + ix * STEP;
    const float gy = -51.2f + iy * STEP;

    int   off[K_], dX[K_], dY[K_];
    float w00[K_], w01[K_], w10[K_], w11[K_];
    bool  val[K_];
    float cnt = 0.0f;

#pragma unroll
    for (int k = 0; k < K_; ++k) {
        const float* E = extr + (size_t)(b * K_ + k) * 16;
        const float* I = intr + (size_t)(b * K_ + k) * 9;
        // world z = 0, w = 1
        const float c0 = E[0] * gx + E[1] * gy + E[3];
        const float c1 = E[4] * gx + E[5] * gy + E[7];
        const float c2 = E[8] * gx + E[9] * gy + E[11];
        const float uu = I[0] * c0 + I[1] * c1 + I[2] * c2;
        const float vv = I[3] * c0 + I[4] * c1 + I[5] * c2;
        const float ww = I[6] * c0 + I[7] * c1 + I[8] * c2;
        const float depth = fmaxf(ww, 1e-5f);
        const float u = uu / depth * 0.125f;   // sx = 88/704
        const float v = vv / depth * 0.125f;   // sy = 32/256
        const bool valid = (ww > 1e-3f) && (u >= 0.0f) && (u <= (float)(WF_ - 1))
                                        && (v >= 0.0f) && (v <= (float)(HF_ - 1));
        const float uc = fminf(fmaxf(u, 0.0f), (float)(WF_ - 1));
        const float vc = fminf(fmaxf(v, 0.0f), (float)(HF_ - 1));
        const float x0f = floorf(uc), y0f = floorf(vc);
        const int x0 = (int)x0f, y0 = (int)y0f;
        const int x1 = min(x0 + 1, WF_ - 1), y1 = min(y0 + 1, HF_ - 1);
        const float wx = uc - x0f, wy = vc - y0f;

        val[k] = valid;
        cnt += valid ? 1.0f : 0.0f;
        w00[k] = (1.0f - wx) * (1.0f - wy);
        w01[k] = wx * (1.0f - wy);
        w10[k] = (1.0f - wx) * wy;
        w11[k] = wx * wy;

        const int pix = y0 * WF_ + x0;
        if (TRANS) {
            off[k] = ((b * K_ + k) * P_ + pix) * C_;
            dX[k]  = (x1 - x0) * C_;
            dY[k]  = (y1 - y0) * (WF_ * C_);
        } else {
            off[k] = (b * K_ + k) * (C_ * P_) + pix;
            dX[k]  = (x1 - x0);
            dY[k]  = (y1 - y0) * WF_;
        }
    }

    const float inv = 1.0f / fmaxf(cnt, 1.0f);
    const int cbeg = cs * CPT;
    float* outp = out + (size_t)b * C_ * NPTS + (size_t)cbeg * NPTS
                      + (size_t)iy * BEV + ix;

    if (TRANS) {
#pragma unroll 1
        for (int c = 0; c < CPT; c += 4) {
            float ax = 0.0f, ay = 0.0f, az = 0.0f, aw = 0.0f;
#pragma unroll
            for (int k = 0; k < K_; ++k) {
                if (!val[k]) continue;
                const float* pb = feat + off[k] + cbeg + c;
                const float4 f00 = *(const float4*)(pb);
                const float4 f01 = *(const float4*)(pb + dX[k]);
                const float4 f10 = *(const float4*)(pb + dY[k]);
                const float4 f11 = *(const float4*)(pb + dX[k] + dY[k]);
                ax += w00[k] * f00.x + w01[k] * f01.x + w10[k] * f10.x + w11[k] * f11.x;
                ay += w00[k] * f00.y + w01[k] * f01.y + w10[k] * f10.y + w11[k] * f11.y;
                az += w00[k] * f00.z + w01[k] * f01.z + w10[k] * f10.z + w11[k] * f11.z;
                aw += w00[k] * f00.w + w01[k] * f01.w + w10[k] * f10.w + w11[k] * f11.w;
            }
            __builtin_nontemporal_store(ax * inv, &outp[(size_t)(c + 0) * NPTS]);
            __builtin_nontemporal_store(ay * inv, &outp[(size_t)(c + 1) * NPTS]);
            __builtin_nontemporal_store(az * inv, &outp[(size_t)(c + 2) * NPTS]);
            __builtin_nontemporal_store(aw * inv, &outp[(size_t)(c + 3) * NPTS]);
        }
    } else {
#pragma unroll 1
        for (int c = 0; c < CPT; ++c) {
            float a = 0.0f;
#pragma unroll
            for (int k = 0; k < K_; ++k) {
                if (!val[k]) continue;
                const float* pb = feat + off[k] + (size_t)(cbeg + c) * P_;
                a += w00[k] * pb[0] + w01[k] * pb[dX[k]]
                   + w10[k] * pb[dY[k]] + w11[k] * pb[dX[k] + dY[k]];
            }
            __builtin_nontemporal_store(a * inv, &outp[(size_t)c * NPTS]);
        }
    }
}

extern "C" void kernel_launch(void* const* d_in, const int* in_sizes, int n_in,
                              void* d_out, int out_size, void* d_ws, size_t ws_size,
                              hipStream_t stream) {
    const float* features   = (const float*)d_in[0];
    const float* intrinsics = (const float*)d_in[1];
    const float* extrinsics = (const float*)d_in[2];
    float* out = (float*)d_out;

    const size_t need = sizeof(float) * (size_t)BK_ * C_ * P_;  // ~33 MB
    if (ws_size >= need) {
        float* featT = (float*)d_ws;
        transpose_feat<<<dim3(P_ / 64, BK_), 256, 0, stream>>>(features, featT);
        bev_project<true><<<dim3(BEV, B_, CSPLIT), 256, 0, stream>>>(
            featT, intrinsics, extrinsics, out);
    } else {
        bev_project<false><<<dim3(BEV, B_, CSPLIT), 256, 0, stream>>>(
            features, intrinsics, extrinsics, out);
    }
}

// Round 3
// 71.731 us; speedup vs baseline: 1.5612x; 1.2863x over previous
//
#include <hip/hip_runtime.h>

#define B_   4
#define K_   6
#define BK_  (B_ * K_)
#define C_   128
#define CB_  (C_ / 4)         // 32 channel-blocks of 4
#define HF_  32
#define WF_  88
#define P_   (HF_ * WF_)      // 2816 pixels per (b,k) feature map
#define BEV  256
#define NPTS (BEV * BEV)      // 65536
#define CSPLIT 4              // channel slices (grid.z)
#define CBPT (CB_ / CSPLIT)   // 8 channel-blocks per thread

// ---------------------------------------------------------------------------
// Kernel 1: shuffle features [BK, C, P] -> [BK, C/4, P, 4] (channel-blocked).
// Each 128-B line then holds one 4-channel block of 8 consecutive pixels:
// bilinear x-corners land in the same line and neighboring BEV lanes share
// lines. LDS-tiled; +1 padding keeps both phases bank-conflict free.
// ---------------------------------------------------------------------------
__global__ __launch_bounds__(256) void shuffle_feat(
    const float* __restrict__ in, float* __restrict__ outT)
{
    __shared__ float lds[64][C_ + 1];
    const int bk  = blockIdx.y;
    const int p0  = blockIdx.x * 64;
    const int tid = threadIdx.x;

    const int pl = tid & 63;        // pixel within tile
    const int cq = tid >> 6;        // 0..3 channel sub-lane (read phase)
    const float* src = in + (size_t)bk * C_ * P_;
#pragma unroll
    for (int c0 = 0; c0 < C_; c0 += 4) {
        const int c = c0 + cq;
        lds[pl][c] = src[(size_t)c * P_ + p0 + pl];
    }
    __syncthreads();

    // write phase: float4 = 4 channels of one pixel, lanes over pixels
    float* dst = outT + (size_t)bk * CB_ * P_ * 4;
    const int cbq = tid >> 6;       // 0..3 cb sub-lane
#pragma unroll
    for (int cb0 = 0; cb0 < CB_; cb0 += 4) {
        const int cb = cb0 + cbq;
        float4 v;
        v.x = lds[pl][cb * 4 + 0];
        v.y = lds[pl][cb * 4 + 1];
        v.z = lds[pl][cb * 4 + 2];
        v.w = lds[pl][cb * 4 + 3];
        *(float4*)(dst + ((size_t)cb * P_ + p0 + pl) * 4) = v;
    }
}

// ---------------------------------------------------------------------------
// Kernel 2: per-BEV-point projection + bilinear sampling over 6 cameras.
// Grid: (BEV rows, B, CSPLIT); block 256 (ix lane). Channel-blocked gathers.
// ---------------------------------------------------------------------------
template <bool TRANS>
__global__ __launch_bounds__(256) void bev_project(
    const float* __restrict__ feat,
    const float* __restrict__ intr,   // [B,K,3,3]
    const float* __restrict__ extr,   // [B,K,4,4]
    float* __restrict__ out)          // [B,C,BEV,BEV]
{
    const int ix = threadIdx.x;
    const int iy = blockIdx.x;
    const int b  = blockIdx.y;
    const int cs = blockIdx.z;

    const float STEP = 102.4f / 255.0f;
    const float gx = -51.2f + ix * STEP;
    const float gy = -51.2f + iy * STEP;

    int   off[K_], dX[K_], dY[K_];
    float w00[K_], w01[K_], w10[K_], w11[K_];
    bool  val[K_];
    float cnt = 0.0f;

#pragma unroll
    for (int k = 0; k < K_; ++k) {
        const float* E = extr + (size_t)(b * K_ + k) * 16;
        const float* I = intr + (size_t)(b * K_ + k) * 9;
        // world z = 0, w = 1
        const float c0 = E[0] * gx + E[1] * gy + E[3];
        const float c1 = E[4] * gx + E[5] * gy + E[7];
        const float c2 = E[8] * gx + E[9] * gy + E[11];
        const float uu = I[0] * c0 + I[1] * c1 + I[2] * c2;
        const float vv = I[3] * c0 + I[4] * c1 + I[5] * c2;
        const float ww = I[6] * c0 + I[7] * c1 + I[8] * c2;
        const float depth = fmaxf(ww, 1e-5f);
        const float u = uu / depth * 0.125f;   // sx = 88/704
        const float v = vv / depth * 0.125f;   // sy = 32/256
        const bool valid = (ww > 1e-3f) && (u >= 0.0f) && (u <= (float)(WF_ - 1))
                                        && (v >= 0.0f) && (v <= (float)(HF_ - 1));
        const float uc = fminf(fmaxf(u, 0.0f), (float)(WF_ - 1));
        const float vc = fminf(fmaxf(v, 0.0f), (float)(HF_ - 1));
        const float x0f = floorf(uc), y0f = floorf(vc);
        const int x0 = (int)x0f, y0 = (int)y0f;
        const int x1 = min(x0 + 1, WF_ - 1), y1 = min(y0 + 1, HF_ - 1);
        const float wx = uc - x0f, wy = vc - y0f;

        val[k] = valid;
        cnt += valid ? 1.0f : 0.0f;
        w00[k] = (1.0f - wx) * (1.0f - wy);
        w01[k] = wx * (1.0f - wy);
        w10[k] = (1.0f - wx) * wy;
        w11[k] = wx * wy;

        const int pix = y0 * WF_ + x0;
        if (TRANS) {
            // base addr (floats) of channel-block 0, this pixel
            off[k] = ((b * K_ + k) * CB_ * P_ + pix) * 4;
            dX[k]  = (x1 - x0) * 4;          // next pixel: 16 B (same line)
            dY[k]  = (y1 - y0) * (WF_ * 4);  // next row
        } else {
            off[k] = (b * K_ + k) * (C_ * P_) + pix;
            dX[k]  = (x1 - x0);
            dY[k]  = (y1 - y0) * WF_;
        }
    }

    const float inv = 1.0f / fmaxf(cnt, 1.0f);
#pragma unroll
    for (int k = 0; k < K_; ++k) {       // fold 1/count into the weights
        w00[k] *= inv; w01[k] *= inv; w10[k] *= inv; w11[k] *= inv;
    }

    float* outp = out + (size_t)b * C_ * NPTS + (size_t)(cs * CBPT * 4) * NPTS
                      + (size_t)iy * BEV + ix;

    if (TRANS) {
#pragma unroll 1
        for (int j = 0; j < CBPT; ++j) {
            const int cb = cs * CBPT + j;
            float ax = 0.0f, ay = 0.0f, az = 0.0f, aw = 0.0f;
#pragma unroll
            for (int k = 0; k < K_; ++k) {
                if (!val[k]) continue;
                const float* pb = feat + off[k] + cb * (P_ * 4);
                const float4 f00 = *(const float4*)(pb);
                const float4 f01 = *(const float4*)(pb + dX[k]);
                const float4 f10 = *(const float4*)(pb + dY[k]);
                const float4 f11 = *(const float4*)(pb + dX[k] + dY[k]);
                ax += w00[k] * f00.x + w01[k] * f01.x + w10[k] * f10.x + w11[k] * f11.x;
                ay += w00[k] * f00.y + w01[k] * f01.y + w10[k] * f10.y + w11[k] * f11.y;
                az += w00[k] * f00.z + w01[k] * f01.z + w10[k] * f10.z + w11[k] * f11.z;
                aw += w00[k] * f00.w + w01[k] * f01.w + w10[k] * f10.w + w11[k] * f11.w;
            }
            __builtin_nontemporal_store(ax, &outp[(size_t)(j * 4 + 0) * NPTS]);
            __builtin_nontemporal_store(ay, &outp[(size_t)(j * 4 + 1) * NPTS]);
            __builtin_nontemporal_store(az, &outp[(size_t)(j * 4 + 2) * NPTS]);
            __builtin_nontemporal_store(aw, &outp[(size_t)(j * 4 + 3) * NPTS]);
        }
    } else {
#pragma unroll 1
        for (int c = 0; c < CBPT * 4; ++c) {
            float a = 0.0f;
#pragma unroll
            for (int k = 0; k < K_; ++k) {
                if (!val[k]) continue;
                const float* pb = feat + off[k] + (size_t)(cs * CBPT * 4 + c) * P_;
                a += w00[k] * pb[0] + w01[k] * pb[dX[k]]
                   + w10[k] * pb[dY[k]] + w11[k] * pb[dX[k] + dY[k]];
            }
            __builtin_nontemporal_store(a, &outp[(size_t)c * NPTS]);
        }
    }
}

extern "C" void kernel_launch(void* const* d_in, const int* in_sizes, int n_in,
                              void* d_out, int out_size, void* d_ws, size_t ws_size,
                              hipStream_t stream) {
    const float* features   = (const float*)d_in[0];
    const float* intrinsics = (const float*)d_in[1];
    const float* extrinsics = (const float*)d_in[2];
    float* out = (float*)d_out;

    const size_t need = sizeof(float) * (size_t)BK_ * C_ * P_;  // ~33 MB
    if (ws_size >= need) {
        float* featT = (float*)d_ws;
        shuffle_feat<<<dim3(P_ / 64, BK_), 256, 0, stream>>>(features, featT);
        bev_project<true><<<dim3(BEV, B_, CSPLIT), 256, 0, stream>>>(
            featT, intrinsics, extrinsics, out);
    } else {
        bev_project<false><<<dim3(BEV, B_, CSPLIT), 256, 0, stream>>>(
            features, intrinsics, extrinsics, out);
    }
}